// Round 8
// baseline (115.753 us; speedup 1.0000x reference)
//
#include <hip/hip_runtime.h>
#include <math.h>

// Gumbel subset (relaxed top-k) — B=2048 rows, N=8192, K=64 softmax steps.
// Multiplicative reformulation: v_i = exp(s0_i - M0), per step:
//   w = v*rinv(S); kh += w; v = fma(-w, v, v); part' = sum(v).
// R8: TWO ROWS PER BLOCK (grid 1024). Each wave carries two independent
// rows' state and reduce chains; the two 6-step shuffle chains interleave
// in the pipeline at the depth of one, and each barrier serves 2 rows of
// work -> serial-chain exposure per unit work halves (R7: ~35% idle, ~1950
// cyc/iter vs ~512 cyc useful issue). Per-row arithmetic identical to R7
// (packed fp16 state, f32 S-reduction on the proven shfl_xor+LDS path).

typedef _Float16 h2 __attribute__((ext_vector_type(2)));

#define BROWS 2048
#define NCOLS 8192
#define KSTEPS 64

#define THREADS 256
#define RPB 2                   // rows per block
#define EPT (NCOLS / THREADS)   // 32 f32 elements per thread per row
#define NPAIR (EPT / 2)         // 16 fp16x2 packs per row
#define NWAVE (THREADS / 64)    // 4

__global__ __launch_bounds__(THREADS, 2) void gumbel_subset_kernel(
    const float* __restrict__ scores,
    const float* __restrict__ g,
    float* __restrict__ out)
{
    const int t = threadIdx.x;
    const size_t baseA = (size_t)(blockIdx.x * RPB) * NCOLS;
    const size_t baseB = baseA + NCOLS;

    // ---- load s0 = scores + g for both rows (coalesced float4) ----
    float sA[EPT], sB[EPT];
    float mA = -INFINITY, mB = -INFINITY;
#pragma unroll
    for (int c = 0; c < EPT / 4; ++c) {
        const int idx = c * (THREADS * 4) + t * 4;
        const float4 a0 = *reinterpret_cast<const float4*>(scores + baseA + idx);
        const float4 g0 = *reinterpret_cast<const float4*>(g + baseA + idx);
        sA[c * 4 + 0] = a0.x + g0.x;
        sA[c * 4 + 1] = a0.y + g0.y;
        sA[c * 4 + 2] = a0.z + g0.z;
        sA[c * 4 + 3] = a0.w + g0.w;
        mA = fmaxf(mA, fmaxf(fmaxf(sA[c * 4 + 0], sA[c * 4 + 1]),
                             fmaxf(sA[c * 4 + 2], sA[c * 4 + 3])));
        const float4 a1 = *reinterpret_cast<const float4*>(scores + baseB + idx);
        const float4 g1 = *reinterpret_cast<const float4*>(g + baseB + idx);
        sB[c * 4 + 0] = a1.x + g1.x;
        sB[c * 4 + 1] = a1.y + g1.y;
        sB[c * 4 + 2] = a1.z + g1.z;
        sB[c * 4 + 3] = a1.w + g1.w;
        mB = fmaxf(mB, fmaxf(fmaxf(sB[c * 4 + 0], sB[c * 4 + 1]),
                             fmaxf(sB[c * 4 + 2], sB[c * 4 + 3])));
    }

    __shared__ float red[2][2 * NWAVE]; // [buf][row*NWAVE + wave], double-buffered
    const int wave = t >> 6;
    const int lane = t & 63;

    // ---- block max reduction for both rows (interleaved chains) ----
#pragma unroll
    for (int off = 32; off > 0; off >>= 1) {
        mA = fmaxf(mA, __shfl_xor(mA, off, 64));
        mB = fmaxf(mB, __shfl_xor(mB, off, 64));
    }
    if (lane == 0) { red[0][wave] = mA; red[0][NWAVE + wave] = mB; }
    __syncthreads();
    mA = fmaxf(fmaxf(red[0][0], red[0][1]), fmaxf(red[0][2], red[0][3]));
    mB = fmaxf(fmaxf(red[0][4], red[0][5]), fmaxf(red[0][6], red[0][7]));
    __syncthreads(); // red[0] is re-written by iteration 0 below

    // ---- v = exp(s0 - M0) packed fp16, kh = 0, initial f32 partials ----
    h2 vA[NPAIR], khA[NPAIR], vB[NPAIR], khB[NPAIR];
    float partA = 0.0f, partB = 0.0f;
#pragma unroll
    for (int p = 0; p < NPAIR; ++p) {
        const float eA0 = __expf(sA[2 * p + 0] - mA);
        const float eA1 = __expf(sA[2 * p + 1] - mA);
        vA[p] = (h2){(_Float16)eA0, (_Float16)eA1};
        khA[p] = (h2){(_Float16)0.0f, (_Float16)0.0f};
        partA += eA0 + eA1;
        const float eB0 = __expf(sB[2 * p + 0] - mB);
        const float eB1 = __expf(sB[2 * p + 1] - mB);
        vB[p] = (h2){(_Float16)eB0, (_Float16)eB1};
        khB[p] = (h2){(_Float16)0.0f, (_Float16)0.0f};
        partB += eB0 + eB1;
    }

    // ---- K relaxation steps ----
#pragma unroll 2
    for (int it = 0; it < KSTEPS; ++it) {
        float sa = partA, sb = partB;
#pragma unroll
        for (int off = 32; off > 0; off >>= 1) {
            sa += __shfl_xor(sa, off, 64);
            sb += __shfl_xor(sb, off, 64);
        }

        const int buf = it & 1;
        if (lane == 0) { red[buf][wave] = sa; red[buf][NWAVE + wave] = sb; }
        __syncthreads();
        const float SA = (red[buf][0] + red[buf][1]) + (red[buf][2] + red[buf][3]);
        const float SB = (red[buf][4] + red[buf][5]) + (red[buf][6] + red[buf][7]);
        const float rAf = __builtin_amdgcn_rcpf(SA);
        const float rBf = __builtin_amdgcn_rcpf(SB);
        const _Float16 rAh = (_Float16)rAf;
        const _Float16 rBh = (_Float16)rBf;
        const h2 rA2 = (h2){rAh, rAh};
        const h2 rB2 = (h2){rBh, rBh};

        h2 z = (h2){(_Float16)0.0f, (_Float16)0.0f};
        h2 aA0 = z, aA1 = z, aB0 = z, aB1 = z;
#pragma unroll
        for (int p = 0; p < NPAIR; p += 2) {
            const h2 wA0 = vA[p + 0] * rA2;
            const h2 wA1 = vA[p + 1] * rA2;
            const h2 wB0 = vB[p + 0] * rB2;
            const h2 wB1 = vB[p + 1] * rB2;
            khA[p + 0] += wA0; khA[p + 1] += wA1;
            khB[p + 0] += wB0; khB[p + 1] += wB1;
            vA[p + 0] = __builtin_elementwise_fma(-wA0, vA[p + 0], vA[p + 0]);
            vA[p + 1] = __builtin_elementwise_fma(-wA1, vA[p + 1], vA[p + 1]);
            vB[p + 0] = __builtin_elementwise_fma(-wB0, vB[p + 0], vB[p + 0]);
            vB[p + 1] = __builtin_elementwise_fma(-wB1, vB[p + 1], vB[p + 1]);
            aA0 += vA[p + 0]; aA1 += vA[p + 1];
            aB0 += vB[p + 0]; aB1 += vB[p + 1];
        }
        const h2 aa = aA0 + aA1;
        const h2 bb = aB0 + aB1;
        partA = (float)aa.x + (float)aa.y;
        partB = (float)bb.x + (float)bb.y;
        // single barrier per iteration: next write targets the other buffer;
        // this buffer is only re-written after the *next* barrier.
    }

    // ---- store khot for both rows (coalesced float4) ----
#pragma unroll
    for (int c = 0; c < EPT / 4; ++c) {
        const int idx = c * (THREADS * 4) + t * 4;
        float4 oA;
        oA.x = (float)khA[2 * c + 0].x;
        oA.y = (float)khA[2 * c + 0].y;
        oA.z = (float)khA[2 * c + 1].x;
        oA.w = (float)khA[2 * c + 1].y;
        *reinterpret_cast<float4*>(out + baseA + idx) = oA;
        float4 oB;
        oB.x = (float)khB[2 * c + 0].x;
        oB.y = (float)khB[2 * c + 0].y;
        oB.z = (float)khB[2 * c + 1].x;
        oB.w = (float)khB[2 * c + 1].y;
        *reinterpret_cast<float4*>(out + baseB + idx) = oB;
    }
}

extern "C" void kernel_launch(void* const* d_in, const int* in_sizes, int n_in,
                              void* d_out, int out_size, void* d_ws, size_t ws_size,
                              hipStream_t stream) {
    const float* scores = (const float*)d_in[0];
    const float* g = (const float*)d_in[1];
    float* out = (float*)d_out;
    (void)in_sizes; (void)n_in; (void)out_size; (void)d_ws; (void)ws_size;

    gumbel_subset_kernel<<<BROWS / RPB, THREADS, 0, stream>>>(scores, g, out);
}

// Round 9
// 111.770 us; speedup vs baseline: 1.0356x; 1.0356x over previous
//
#include <hip/hip_runtime.h>
#include <math.h>

// Gumbel subset (relaxed top-k) — B=2048 rows, N=8192, K=64 softmax steps.
// Multiplicative reformulation: v_i = exp(s0_i - M0), per step:
//   w = v*rinv(S); kh += w; v = fma(-w, v, v); part' = sum(v).
// R9: R6's proven f32 skeleton, but state/updates as PACKED FP32 float2 ->
// v_pk_{mul,add,fma}_f32 (2 f32/instr, full rate, exact f32 semantics).
// R6 accounting: busy 67us == 158 instr/thread/iter exactly => issue-bound;
// R7's fp16 scalarized (busy unchanged). Packed f32 cuts the inner loop
// 128->64 instr (94 total w/ overhead) with zero precision risk.
// launch_bounds(256,4): need ~90 regs -> ~5 waves/SIMD to hide reduce chain.

typedef float f2 __attribute__((ext_vector_type(2)));

#define BROWS 2048
#define NCOLS 8192
#define KSTEPS 64

#define THREADS 256
#define EPT (NCOLS / THREADS)  // 32 f32 elements per thread
#define NPK (EPT / 2)          // 16 float2 packs
#define NWAVE (THREADS / 64)   // 4

__global__ __launch_bounds__(THREADS, 4) void gumbel_subset_kernel(
    const float* __restrict__ scores,
    const float* __restrict__ g,
    float* __restrict__ out)
{
    const int row = blockIdx.x;
    const int t = threadIdx.x;
    const float* __restrict__ srow = scores + (size_t)row * NCOLS;
    const float* __restrict__ grow = g + (size_t)row * NCOLS;
    float* __restrict__ orow = out + (size_t)row * NCOLS;

    f2 v[NPK];   // softmax weights (packed pairs)
    f2 kh[NPK];  // khot accumulator

    // ---- load s0 = scores + g (coalesced float4) into packs, local max ----
    // local elem k <-> global idx (k/4)*1024 + t*4 + (k%4); pack p = elems 2p,2p+1
    f2 mx2 = (f2){-INFINITY, -INFINITY};
#pragma unroll
    for (int c = 0; c < EPT / 4; ++c) {
        const int idx = c * (THREADS * 4) + t * 4;
        const float4 a = *reinterpret_cast<const float4*>(srow + idx);
        const float4 b = *reinterpret_cast<const float4*>(grow + idx);
        const f2 p0 = (f2){a.x + b.x, a.y + b.y};
        const f2 p1 = (f2){a.z + b.z, a.w + b.w};
        v[2 * c + 0] = p0;
        v[2 * c + 1] = p1;
        mx2 = __builtin_elementwise_max(mx2, __builtin_elementwise_max(p0, p1));
    }
    float m = fmaxf(mx2.x, mx2.y);

    __shared__ float red[2][NWAVE]; // double-buffered per-wave partials
    const int wave = t >> 6;
    const int lane = t & 63;

    // ---- block max reduction (once) ----
#pragma unroll
    for (int off = 32; off > 0; off >>= 1)
        m = fmaxf(m, __shfl_xor(m, off, 64));
    if (lane == 0) red[0][wave] = m;
    __syncthreads();
    m = fmaxf(fmaxf(red[0][0], red[0][1]), fmaxf(red[0][2], red[0][3]));
    __syncthreads(); // red[0] is re-written by iteration 0 below

    // ---- v = exp(s0 - M0), kh = 0, initial partial sums ----
    f2 acc0 = (f2){0.0f, 0.0f};
    f2 acc1 = acc0;
#pragma unroll
    for (int p = 0; p < NPK; p += 2) {
        v[p + 0] = (f2){__expf(v[p + 0].x - m), __expf(v[p + 0].y - m)};
        v[p + 1] = (f2){__expf(v[p + 1].x - m), __expf(v[p + 1].y - m)};
        kh[p + 0] = (f2){0.0f, 0.0f};
        kh[p + 1] = (f2){0.0f, 0.0f};
        acc0 += v[p + 0];
        acc1 += v[p + 1];
    }
    float part = (acc0.x + acc0.y) + (acc1.x + acc1.y);

    // ---- K relaxation steps ----
#pragma unroll 2
    for (int it = 0; it < KSTEPS; ++it) {
        float s = part;
#pragma unroll
        for (int off = 32; off > 0; off >>= 1)
            s += __shfl_xor(s, off, 64);

        const int buf = it & 1;
        if (lane == 0) red[buf][wave] = s;
        __syncthreads();
        const float S = (red[buf][0] + red[buf][1]) + (red[buf][2] + red[buf][3]);
        const float rinv = __builtin_amdgcn_rcpf(S);
        const f2 r2 = (f2){rinv, rinv};

        f2 a0 = (f2){0.0f, 0.0f};
        f2 a1 = a0, a2 = a0, a3 = a0;
#pragma unroll
        for (int p = 0; p < NPK; p += 4) {
            const f2 w0 = v[p + 0] * r2;                       // v_pk_mul_f32
            const f2 w1 = v[p + 1] * r2;
            const f2 w2 = v[p + 2] * r2;
            const f2 w3 = v[p + 3] * r2;
            kh[p + 0] += w0; kh[p + 1] += w1;                  // v_pk_add_f32
            kh[p + 2] += w2; kh[p + 3] += w3;
            v[p + 0] = __builtin_elementwise_fma(-w0, v[p + 0], v[p + 0]); // v_pk_fma_f32
            v[p + 1] = __builtin_elementwise_fma(-w1, v[p + 1], v[p + 1]);
            v[p + 2] = __builtin_elementwise_fma(-w2, v[p + 2], v[p + 2]);
            v[p + 3] = __builtin_elementwise_fma(-w3, v[p + 3], v[p + 3]);
            a0 += v[p + 0]; a1 += v[p + 1];                    // v_pk_add_f32
            a2 += v[p + 2]; a3 += v[p + 3];
        }
        const f2 aa = (a0 + a1) + (a2 + a3);
        part = aa.x + aa.y;
        // single barrier per iteration: next write targets the other buffer;
        // this buffer is only re-written after the *next* barrier.
    }

    // ---- store khot (coalesced float4) ----
#pragma unroll
    for (int c = 0; c < EPT / 4; ++c) {
        const int idx = c * (THREADS * 4) + t * 4;
        float4 o;
        o.x = kh[2 * c + 0].x;
        o.y = kh[2 * c + 0].y;
        o.z = kh[2 * c + 1].x;
        o.w = kh[2 * c + 1].y;
        *reinterpret_cast<float4*>(orow + idx) = o;
    }
}

extern "C" void kernel_launch(void* const* d_in, const int* in_sizes, int n_in,
                              void* d_out, int out_size, void* d_ws, size_t ws_size,
                              hipStream_t stream) {
    const float* scores = (const float*)d_in[0];
    const float* g = (const float*)d_in[1];
    float* out = (float*)d_out;
    (void)in_sizes; (void)n_in; (void)out_size; (void)d_ws; (void)ws_size;

    gumbel_subset_kernel<<<BROWS, THREADS, 0, stream>>>(scores, g, out);
}